// Round 1
// baseline (307.436 us; speedup 1.0000x reference)
//
#include <hip/hip_runtime.h>
#include <cstdint>

typedef __bf16 bf16x8 __attribute__((ext_vector_type(8)));
typedef short  s16x8  __attribute__((ext_vector_type(8)));
typedef float  f32x4  __attribute__((ext_vector_type(4)));
typedef unsigned int uint32;
typedef unsigned long long u64;

#define SB 2048
#define DD 1024
#define HH 16
#define HDD 64
#define BB 2
#define SCALEF 0.16875f      /* 1.35 / sqrt(64) */
#define NEGBIG (-1.35e9f)    /* -1e9 * 1.35 (masked score after focus factor) */

__device__ __forceinline__ ushort f2bf(float f){
  uint32 u = __builtin_bit_cast(uint32, f);
  u += 0x7fffu + ((u >> 16) & 1u);
  return (ushort)(u >> 16);
}
__device__ __forceinline__ bf16x8 ldb128(const void* p){
  return __builtin_bit_cast(bf16x8, *(const s16x8*)p);
}
__device__ __forceinline__ void gl_lds16(const void* g, void* l){
  __builtin_amdgcn_global_load_lds((const __attribute__((address_space(1))) void*)g,
                                   (__attribute__((address_space(3))) void*)l, 16, 0, 0);
}

// ---------------- convert f32 -> bf16 ----------------
__global__ __launch_bounds__(256) void k_cvt(const float* __restrict__ in,
                                             ushort* __restrict__ out, int n4){
  int i = blockIdx.x * 256 + threadIdx.x;
  if (i < n4){
    float4 v = ((const float4*)in)[i];
    ushort4 o;
    o.x = f2bf(v.x); o.y = f2bf(v.y); o.z = f2bf(v.z); o.w = f2bf(v.w);
    ((ushort4*)out)[i] = o;
  }
}

// ---------------- pack mask ints into 64-bit words ----------------
__global__ __launch_bounds__(256) void k_pack(const int* __restrict__ mask,
                                              u64* __restrict__ bits){
  int i = blockIdx.x * 256 + threadIdx.x;
  u64 b = __ballot(mask[i] != 0);
  if ((threadIdx.x & 63) == 0) bits[i >> 6] = b;
}

// ---------------- generic GEMM: C[r][n] = sum_k A[r][k]*W[n][k] + bias[n] -----
// 128x128 tile, BK=32, 256 threads (4 waves, 2x2), MODE 0: write QKV proj bf16
// into [B,H,S,hd]; MODE 1: write f32 to d_out [B*S, D].
template<int MODE>
__device__ __forceinline__ void gemm_body(
    const ushort* __restrict__ A, const ushort* __restrict__ W,
    const float* __restrict__ bias, ushort* __restrict__ outp, float* __restrict__ outf)
{
  __shared__ ushort lsA[128*32];
  __shared__ ushort lsB[128*32];
  const int t = threadIdx.x;
  const int l = t & 63, w = t >> 6;
  const int g16 = l >> 4, r16 = l & 15;
  const int wr = w >> 1, wc = w & 1;
  const int rowBase = blockIdx.y * 128;
  const int colBase = blockIdx.x * 128;
  f32x4 zero = {0.f, 0.f, 0.f, 0.f};
  f32x4 acc[4][4];
  #pragma unroll
  for (int m = 0; m < 4; m++)
    #pragma unroll
    for (int n = 0; n < 4; n++) acc[m][n] = zero;

  for (int kt = 0; kt < 32; ++kt){
    __syncthreads();
    #pragma unroll
    for (int i = 0; i < 2; i++){
      int c = t + i * 256;            // linear 16B chunk id, 512 per tile
      int row = c >> 2, cin = c & 3;
      int g = cin ^ ((row >> 1) & 3); // inverse swizzle on global source
      gl_lds16(A + (size_t)(rowBase + row) * DD + kt * 32 + g * 8, (char*)lsA + c * 16);
      gl_lds16(W + (size_t)(colBase + row) * DD + kt * 32 + g * 8, (char*)lsB + c * 16);
    }
    __syncthreads();
    bf16x8 af[4], bfr[4];
    #pragma unroll
    for (int m = 0; m < 4; m++){
      int row = wr * 64 + m * 16 + r16;
      af[m] = ldb128((char*)lsA + row * 64 + ((g16 ^ ((row >> 1) & 3)) << 4));
    }
    #pragma unroll
    for (int n = 0; n < 4; n++){
      int row = wc * 64 + n * 16 + r16;
      bfr[n] = ldb128((char*)lsB + row * 64 + ((g16 ^ ((row >> 1) & 3)) << 4));
    }
    #pragma unroll
    for (int m = 0; m < 4; m++)
      #pragma unroll
      for (int n = 0; n < 4; n++)
        acc[m][n] = __builtin_amdgcn_mfma_f32_16x16x32_bf16(af[m], bfr[n], acc[m][n], 0, 0, 0);
  }
  // epilogue (C/D map: col = lane&15, row = (lane>>4)*4 + j  [verified])
  #pragma unroll
  for (int m = 0; m < 4; m++){
    #pragma unroll
    for (int n = 0; n < 4; n++){
      int ng = colBase + wc * 64 + n * 16 + r16;
      float bval = bias[ng];
      #pragma unroll
      for (int j = 0; j < 4; j++){
        int r = rowBase + wr * 64 + m * 16 + g16 * 4 + j;
        float v = acc[m][n][j] + bval;
        if (MODE == 0){
          int h = ng >> 6, d = ng & 63;
          int b = r >> 11, s = r & 2047;
          outp[(((size_t)(b * HH + h) * SB + s) << 6) + d] = f2bf(v);
        } else {
          outf[(size_t)r * DD + ng] = v;
        }
      }
    }
  }
}

__global__ __launch_bounds__(256) void k_gemm_qkv(
    const ushort* __restrict__ A,
    const ushort* __restrict__ Wq, const ushort* __restrict__ Wk, const ushort* __restrict__ Wv,
    const float* __restrict__ bq, const float* __restrict__ bk, const float* __restrict__ bv,
    ushort* __restrict__ Q, ushort* __restrict__ K, ushort* __restrict__ V)
{
  int z = blockIdx.z;
  const ushort* W = (z == 0) ? Wq : ((z == 1) ? Wk : Wv);
  const float* bi = (z == 0) ? bq : ((z == 1) ? bk : bv);
  ushort* o = (z == 0) ? Q : ((z == 1) ? K : V);
  gemm_body<0>(A, W, bi, o, nullptr);
}

__global__ __launch_bounds__(256) void k_gemm_out(
    const ushort* __restrict__ A, const ushort* __restrict__ Wo,
    const float* __restrict__ bo, float* __restrict__ out)
{
  gemm_body<1>(A, Wo, bo, nullptr, out);
}

// ---------------- flash attention: per (b, h, 64-row q tile) ----------------
// Stores attended (bf16, [B,S,D] with D = h*64+d) and per-row m, 1/l.
__global__ __launch_bounds__(256) void k_flash(
    const ushort* __restrict__ Q, const ushort* __restrict__ K, const ushort* __restrict__ V,
    const u64* __restrict__ mbits,
    ushort* __restrict__ att, float* __restrict__ marr, float* __restrict__ ilarr)
{
  __shared__ ushort lsK[64*64];   // [kpos][hd], swizzled 16B chunks
  __shared__ ushort lsV[64*64];   // transposed: [hd][kpos], swizzled
  __shared__ ushort lsP[4*16*64]; // per-wave P tile [16 q][64 kpos], swizzled
  const int t = threadIdx.x;
  const int l = t & 63, w = t >> 6;
  const int g16 = l >> 4, r16 = l & 15;
  const int b = blockIdx.z, h = blockIdx.y, qt = blockIdx.x;
  const size_t ho = ((size_t)(b * HH + h)) * SB * HDD;
  const int qbase = qt * 64;
  const int qr0 = qbase + w * 16 + g16 * 4;   // this lane's 4 rows start

  bf16x8 aq[2];
  {
    int qrow = qbase + w * 16 + r16;
    #pragma unroll
    for (int ks = 0; ks < 2; ++ks)
      aq[ks] = ldb128(Q + ho + (size_t)qrow * HDD + ks * 32 + g16 * 8);
  }
  f32x4 zero = {0.f, 0.f, 0.f, 0.f};
  f32x4 acc[4];
  #pragma unroll
  for (int c = 0; c < 4; c++) acc[c] = zero;
  float mrun[4], lrun[4];
  #pragma unroll
  for (int j = 0; j < 4; j++){ mrun[j] = -3.0e38f; lrun[j] = 0.f; }

  for (int kt = 0; kt < 32; ++kt){
    __syncthreads();
    // stage K via global_load_lds (linear dest, pre-swizzled source)
    #pragma unroll
    for (int i = 0; i < 2; i++){
      int c = t + i * 256;
      int r = c >> 3, cg = c & 7;
      int g = cg ^ (r & 7);
      gl_lds16(K + ho + (size_t)(kt * 64 + r) * HDD + g * 8, (char*)lsK + c * 16);
    }
    // stage V transposed through registers
    {
      int c0 = t;       int ra = c0 >> 3, ca = c0 & 7;
      int c1 = t + 256; int rb = c1 >> 3, cb = c1 & 7;
      s16x8 v0 = *(const s16x8*)(V + ho + (size_t)(kt * 64 + ra) * HDD + ca * 8);
      s16x8 v1 = *(const s16x8*)(V + ho + (size_t)(kt * 64 + rb) * HDD + cb * 8);
      #pragma unroll
      for (int j = 0; j < 8; j++){
        int d0 = ca * 8 + j;
        *(ushort*)((char*)lsV + d0 * 128 + (((ra >> 3) ^ (d0 & 7)) << 4) + ((ra & 7) << 1)) = (ushort)v0[j];
      }
      #pragma unroll
      for (int j = 0; j < 8; j++){
        int d1 = cb * 8 + j;
        *(ushort*)((char*)lsV + d1 * 128 + (((rb >> 3) ^ (d1 & 7)) << 4) + ((rb & 7) << 1)) = (ushort)v1[j];
      }
    }
    __syncthreads();

    // QK^T : scores 16q x 64k per wave
    f32x4 sc[4];
    #pragma unroll
    for (int f = 0; f < 4; ++f){
      int row = 16 * f + r16;
      bf16x8 b0 = ldb128((char*)lsK + row * 128 + (((0 + g16) ^ (row & 7)) << 4));
      bf16x8 b1 = ldb128((char*)lsK + row * 128 + (((4 + g16) ^ (row & 7)) << 4));
      f32x4 z = zero;
      z = __builtin_amdgcn_mfma_f32_16x16x32_bf16(aq[0], b0, z, 0, 0, 0);
      z = __builtin_amdgcn_mfma_f32_16x16x32_bf16(aq[1], b1, z, 0, 0, 0);
      sc[f] = z;
    }
    // mask + scale
    u64 mw[4];
    #pragma unroll
    for (int j = 0; j < 4; j++)
      mw[j] = mbits[((size_t)b * SB + (qr0 + j)) * 32 + kt];
    float sv[4][4];
    #pragma unroll
    for (int f = 0; f < 4; ++f)
      #pragma unroll
      for (int j = 0; j < 4; j++){
        int kl = 16 * f + r16;
        sv[f][j] = ((mw[j] >> kl) & 1ull) ? sc[f][j] * SCALEF : NEGBIG;
      }
    // online softmax update (rows live across the 16 lanes sharing l>>4)
    #pragma unroll
    for (int j = 0; j < 4; j++){
      float mx = fmaxf(fmaxf(sv[0][j], sv[1][j]), fmaxf(sv[2][j], sv[3][j]));
      mx = fmaxf(mx, __shfl_xor(mx, 1, 64));
      mx = fmaxf(mx, __shfl_xor(mx, 2, 64));
      mx = fmaxf(mx, __shfl_xor(mx, 4, 64));
      mx = fmaxf(mx, __shfl_xor(mx, 8, 64));
      float mnew = fmaxf(mrun[j], mx);
      float alpha = __expf(mrun[j] - mnew);
      mrun[j] = mnew;
      lrun[j] *= alpha;
      #pragma unroll
      for (int c = 0; c < 4; c++) acc[c][j] *= alpha;
      float rs = 0.f;
      #pragma unroll
      for (int f = 0; f < 4; f++){
        float p = __expf(sv[f][j] - mnew);
        sv[f][j] = p;
        rs += p;
      }
      rs += __shfl_xor(rs, 1, 64);
      rs += __shfl_xor(rs, 2, 64);
      rs += __shfl_xor(rs, 4, 64);
      rs += __shfl_xor(rs, 8, 64);
      lrun[j] += rs;
    }
    // write P (wave-private LDS region, no barrier needed)
    #pragma unroll
    for (int f = 0; f < 4; ++f)
      #pragma unroll
      for (int j = 0; j < 4; j++){
        int prow = g16 * 4 + j;
        int pcol = 16 * f + r16;
        int off = w * 2048 + prow * 128 + ((((pcol >> 3) ^ (prow & 7))) << 4) + ((pcol & 7) << 1);
        *(ushort*)((char*)lsP + off) = f2bf(sv[f][j]);
      }
    // PV
    #pragma unroll
    for (int ks2 = 0; ks2 < 2; ++ks2){
      bf16x8 pa = ldb128((char*)lsP + w * 2048 + r16 * 128 + (((ks2 * 4 + g16) ^ (r16 & 7)) << 4));
      #pragma unroll
      for (int c = 0; c < 4; c++){
        int row = 16 * c + r16;
        bf16x8 bv_ = ldb128((char*)lsV + row * 128 + (((ks2 * 4 + g16) ^ (row & 7)) << 4));
        acc[c] = __builtin_amdgcn_mfma_f32_16x16x32_bf16(pa, bv_, acc[c], 0, 0, 0);
      }
    }
  }
  // epilogue
  #pragma unroll
  for (int j = 0; j < 4; j++){
    float il = 1.0f / lrun[j];
    int orow = qr0 + j;
    #pragma unroll
    for (int c = 0; c < 4; c++)
      att[((size_t)b * SB + orow) * DD + h * HDD + c * 16 + r16] = f2bf(acc[c][j] * il);
    if (r16 == 0){
      marr [(size_t)(b * HH + h) * SB + orow] = mrun[j];
      ilarr[(size_t)(b * HH + h) * SB + orow] = il;
    }
  }
}

// ---------------- avg attention: per (b, 64-q tile, 64-k tile), loop heads ----
__global__ __launch_bounds__(256) void k_avg(
    const ushort* __restrict__ Q, const ushort* __restrict__ K,
    const u64* __restrict__ mbits, const float* __restrict__ marr,
    const float* __restrict__ ilarr, float* __restrict__ avg)
{
  __shared__ ushort lsQ[64*64];
  __shared__ ushort lsK[64*64];
  const int t = threadIdx.x;
  const int l = t & 63, w = t >> 6;
  const int g16 = l >> 4, r16 = l & 15;
  const int b = blockIdx.z, qt = blockIdx.y, kt = blockIdx.x;
  const int qbase = qt * 64, kbase = kt * 64;
  const int qr0 = qbase + w * 16 + g16 * 4;
  u64 mw[4];
  #pragma unroll
  for (int j = 0; j < 4; j++)
    mw[j] = mbits[((size_t)b * SB + qr0 + j) * 32 + kt];
  f32x4 zero = {0.f, 0.f, 0.f, 0.f};
  f32x4 acc[4];
  #pragma unroll
  for (int c = 0; c < 4; c++) acc[c] = zero;

  for (int h = 0; h < HH; ++h){
    const size_t ho = ((size_t)(b * HH + h)) * SB * HDD;
    __syncthreads();
    #pragma unroll
    for (int i = 0; i < 2; i++){
      int c = t + i * 256;
      int r = c >> 3, cg = c & 7;
      int g = cg ^ (r & 7);
      gl_lds16(Q + ho + (size_t)(qbase + r) * HDD + g * 8, (char*)lsQ + c * 16);
      gl_lds16(K + ho + (size_t)(kbase + r) * HDD + g * 8, (char*)lsK + c * 16);
    }
    __syncthreads();
    int qrow = w * 16 + r16;
    bf16x8 a0 = ldb128((char*)lsQ + qrow * 128 + (((0 + g16) ^ (qrow & 7)) << 4));
    bf16x8 a1 = ldb128((char*)lsQ + qrow * 128 + (((4 + g16) ^ (qrow & 7)) << 4));
    float mh[4], ilh[4];
    #pragma unroll
    for (int j = 0; j < 4; j++){
      mh[j]  = marr [(size_t)(b * HH + h) * SB + qr0 + j];
      ilh[j] = ilarr[(size_t)(b * HH + h) * SB + qr0 + j];
    }
    #pragma unroll
    for (int f = 0; f < 4; ++f){
      int row = 16 * f + r16;
      bf16x8 b0 = ldb128((char*)lsK + row * 128 + (((0 + g16) ^ (row & 7)) << 4));
      bf16x8 b1 = ldb128((char*)lsK + row * 128 + (((4 + g16) ^ (row & 7)) << 4));
      f32x4 z = zero;
      z = __builtin_amdgcn_mfma_f32_16x16x32_bf16(a0, b0, z, 0, 0, 0);
      z = __builtin_amdgcn_mfma_f32_16x16x32_bf16(a1, b1, z, 0, 0, 0);
      #pragma unroll
      for (int j = 0; j < 4; j++){
        int kl = 16 * f + r16;
        float s = ((mw[j] >> kl) & 1ull) ? z[j] * SCALEF : NEGBIG;
        acc[f][j] += __expf(s - mh[j]) * ilh[j];
      }
    }
  }
  #pragma unroll
  for (int f = 0; f < 4; f++)
    #pragma unroll
    for (int j = 0; j < 4; j++){
      int qr = qr0 + j;
      int kc = kbase + 16 * f + r16;
      avg[((size_t)b * SB + qr) * SB + kc] = acc[f][j] * 0.0625f;
    }
}

// ---------------- launch ----------------
extern "C" void kernel_launch(void* const* d_in, const int* in_sizes, int n_in,
                              void* d_out, int out_size, void* d_ws, size_t ws_size,
                              hipStream_t stream)
{
  const float* x  = (const float*)d_in[0];
  const int* mask = (const int*)d_in[1];
  const float* Wq = (const float*)d_in[2];
  const float* bq = (const float*)d_in[3];
  const float* Wk = (const float*)d_in[4];
  const float* bk = (const float*)d_in[5];
  const float* Wv = (const float*)d_in[6];
  const float* bv = (const float*)d_in[7];
  const float* Wo = (const float*)d_in[8];
  const float* bo = (const float*)d_in[9];
  float* out = (float*)d_out;
  float* avg = out + (size_t)BB * SB * DD;

  char* ws = (char*)d_ws;                       // ~50 MB used
  ushort* xb   = (ushort*)(ws);                 // [4096][1024] bf16, 8 MB
  ushort* wqb  = (ushort*)(ws + (8ull  << 20)); // 2 MB each
  ushort* wkb  = (ushort*)(ws + (10ull << 20));
  ushort* wvb  = (ushort*)(ws + (12ull << 20));
  ushort* wob  = (ushort*)(ws + (14ull << 20));
  ushort* Qb   = (ushort*)(ws + (16ull << 20)); // [B,H,S,hd] bf16, 8 MB each
  ushort* Kb   = (ushort*)(ws + (24ull << 20));
  ushort* Vb   = (ushort*)(ws + (32ull << 20));
  ushort* att  = (ushort*)(ws + (40ull << 20)); // [B,S,D] bf16, 8 MB
  float*  marr = (float*) (ws + (48ull << 20)); // [B,H,S] f32
  float*  ilarr= (float*) (ws + (48ull << 20) + (1ull << 19));
  u64*    mbits= (u64*)   (ws + (49ull << 20)); // [B,S,S/64] u64, 1 MB

  k_cvt<<<4096, 256, 0, stream>>>(x,  xb,  1048576);
  k_cvt<<<1024, 256, 0, stream>>>(Wq, wqb, 262144);
  k_cvt<<<1024, 256, 0, stream>>>(Wk, wkb, 262144);
  k_cvt<<<1024, 256, 0, stream>>>(Wv, wvb, 262144);
  k_cvt<<<1024, 256, 0, stream>>>(Wo, wob, 262144);
  k_pack<<<32768, 256, 0, stream>>>(mask, mbits);
  k_gemm_qkv<<<dim3(8, 32, 3), 256, 0, stream>>>(xb, wqb, wkb, wvb, bq, bk, bv, Qb, Kb, Vb);
  k_flash<<<dim3(32, 16, 2), 256, 0, stream>>>(Qb, Kb, Vb, mbits, att, marr, ilarr);
  k_avg<<<dim3(32, 32, 2), 256, 0, stream>>>(Qb, Kb, mbits, marr, ilarr, avg);
  k_gemm_out<<<dim3(8, 32, 1), 256, 0, stream>>>(att, wob, bo, out);
}

// Round 3
// 247.698 us; speedup vs baseline: 1.2412x; 1.2412x over previous
//
#include <hip/hip_runtime.h>
#include <cstdint>

typedef __bf16 bf16x8 __attribute__((ext_vector_type(8)));
typedef short  s16x8  __attribute__((ext_vector_type(8)));
typedef float  f32x4  __attribute__((ext_vector_type(4)));
typedef unsigned int uint32;
typedef uint32 u32x2 __attribute__((ext_vector_type(2)));
typedef unsigned long long u64;

#define SB 2048
#define DD 1024
#define HH 16
#define HDD 64
#define BB 2
#define C2LOG 0.2434547882f        /* (1.35/sqrt(64)) * log2(e) */
#define NEGBIG2 (-1.9476383e9f)    /* -1e9 * 1.35 * log2(e) */

__device__ __forceinline__ ushort f2bf(float f){
  uint32 u = __builtin_bit_cast(uint32, f);
  u += 0x7fffu + ((u >> 16) & 1u);
  return (ushort)(u >> 16);
}
__device__ __forceinline__ uint32 packbf(float a, float b){
  return (uint32)f2bf(a) | ((uint32)f2bf(b) << 16);
}
__device__ __forceinline__ bf16x8 ldb128(const void* p){
  return __builtin_bit_cast(bf16x8, *(const s16x8*)p);
}
__device__ __forceinline__ void gl_lds16(const void* g, void* l){
  __builtin_amdgcn_global_load_lds((const __attribute__((address_space(1))) void*)g,
                                   (__attribute__((address_space(3))) void*)l, 16, 0, 0);
}

// ---------------- convert f32 -> bf16 ----------------
__global__ __launch_bounds__(256) void k_cvt(const float* __restrict__ in,
                                             ushort* __restrict__ out, int n4){
  int i = blockIdx.x * 256 + threadIdx.x;
  if (i < n4){
    float4 v = ((const float4*)in)[i];
    ushort4 o;
    o.x = f2bf(v.x); o.y = f2bf(v.y); o.z = f2bf(v.z); o.w = f2bf(v.w);
    ((ushort4*)out)[i] = o;
  }
}

// ---------------- pack mask ints into 64-bit words ----------------
__global__ __launch_bounds__(256) void k_pack(const int* __restrict__ mask,
                                              u64* __restrict__ bits){
  int i = blockIdx.x * 256 + threadIdx.x;
  u64 b = __ballot(mask[i] != 0);
  if ((threadIdx.x & 63) == 0) bits[i >> 6] = b;
}

// ---------------- generic GEMM: C[r][n] = sum_k A[r][k]*W[n][k] + bias[n] -----
// MODE 0: write bf16 to [B,H,S,hd]; MODE 1: write f32 [B*S,D]; MODE 2: write
// bf16 transposed to [B,H,hd,S].
template<int MODE>
__device__ __forceinline__ void gemm_body(
    const ushort* __restrict__ A, const ushort* __restrict__ W,
    const float* __restrict__ bias, ushort* __restrict__ outp, float* __restrict__ outf)
{
  __shared__ ushort lsA[128*32];
  __shared__ ushort lsB[128*32];
  const int t = threadIdx.x;
  const int l = t & 63, w = t >> 6;
  const int g16 = l >> 4, r16 = l & 15;
  const int wr = w >> 1, wc = w & 1;
  const int rowBase = blockIdx.y * 128;
  const int colBase = blockIdx.x * 128;
  f32x4 zero = {0.f, 0.f, 0.f, 0.f};
  f32x4 acc[4][4];
  #pragma unroll
  for (int m = 0; m < 4; m++)
    #pragma unroll
    for (int n = 0; n < 4; n++) acc[m][n] = zero;

  for (int kt = 0; kt < 32; ++kt){
    __syncthreads();
    #pragma unroll
    for (int i = 0; i < 2; i++){
      int c = t + i * 256;
      int row = c >> 2, cin = c & 3;
      int g = cin ^ ((row >> 1) & 3);
      gl_lds16(A + (size_t)(rowBase + row) * DD + kt * 32 + g * 8, (char*)lsA + c * 16);
      gl_lds16(W + (size_t)(colBase + row) * DD + kt * 32 + g * 8, (char*)lsB + c * 16);
    }
    __syncthreads();
    bf16x8 af[4], bfr[4];
    #pragma unroll
    for (int m = 0; m < 4; m++){
      int row = wr * 64 + m * 16 + r16;
      af[m] = ldb128((char*)lsA + row * 64 + ((g16 ^ ((row >> 1) & 3)) << 4));
    }
    #pragma unroll
    for (int n = 0; n < 4; n++){
      int row = wc * 64 + n * 16 + r16;
      bfr[n] = ldb128((char*)lsB + row * 64 + ((g16 ^ ((row >> 1) & 3)) << 4));
    }
    #pragma unroll
    for (int m = 0; m < 4; m++)
      #pragma unroll
      for (int n = 0; n < 4; n++)
        acc[m][n] = __builtin_amdgcn_mfma_f32_16x16x32_bf16(af[m], bfr[n], acc[m][n], 0, 0, 0);
  }
  #pragma unroll
  for (int m = 0; m < 4; m++){
    #pragma unroll
    for (int n = 0; n < 4; n++){
      int ng = colBase + wc * 64 + n * 16 + r16;
      float bval = bias[ng];
      #pragma unroll
      for (int j = 0; j < 4; j++){
        int r = rowBase + wr * 64 + m * 16 + g16 * 4 + j;
        float v = acc[m][n][j] + bval;
        if (MODE == 0){
          int h = ng >> 6, d = ng & 63;
          int b = r >> 11, s = r & 2047;
          outp[(((size_t)(b * HH + h) * SB + s) << 6) + d] = f2bf(v);
        } else if (MODE == 2){
          int h = ng >> 6, d = ng & 63;
          int b = r >> 11, s = r & 2047;
          outp[((size_t)(b * HH + h) * HDD + d) * SB + s] = f2bf(v);
        } else {
          outf[(size_t)r * DD + ng] = v;
        }
      }
    }
  }
}

__global__ __launch_bounds__(256) void k_gemm_qk(
    const ushort* __restrict__ A,
    const ushort* __restrict__ Wq, const ushort* __restrict__ Wk,
    const float* __restrict__ bq, const float* __restrict__ bk,
    ushort* __restrict__ Q, ushort* __restrict__ K)
{
  int z = blockIdx.z;
  gemm_body<0>(A, z ? Wk : Wq, z ? bk : bq, z ? K : Q, nullptr);
}

__global__ __launch_bounds__(256) void k_gemm_v(
    const ushort* __restrict__ A, const ushort* __restrict__ Wv,
    const float* __restrict__ bv, ushort* __restrict__ Vt)
{
  gemm_body<2>(A, Wv, bv, Vt, nullptr);
}

__global__ __launch_bounds__(256) void k_gemm_out(
    const ushort* __restrict__ A, const ushort* __restrict__ Wo,
    const float* __restrict__ bo, float* __restrict__ out)
{
  gemm_body<1>(A, Wo, bo, nullptr, out);
}

// ---------------- flash attention (swapped QK^T, P via wave-private LDS) -----
// 8 waves x 16 q-rows = 128 q-rows/block; KVBLK=64, double-buffered K/Vt LDS.
// lsK: [64 k][64 d] row-major, 16B-chunk XOR swizzle (chunk ^= row&7).
// lsV: [64 d][64 s] row-major (V^T), same swizzle.
// lsP: per-wave [16 q][64 k] row-major, same swizzle.
__device__ __forceinline__ void stage_kv(const ushort* __restrict__ Kp,
                                         const ushort* __restrict__ Vtp,
                                         ushort* dK, ushort* dV, int t){
  int r = t >> 3, g = (t & 7) ^ (r & 7);
  gl_lds16(Kp + (size_t)r * HDD + g * 8, (char*)dK + t * 16);
  gl_lds16(Vtp + (size_t)r * SB + g * 8, (char*)dV + t * 16);
}

__global__ __launch_bounds__(512) void k_flash(
    const ushort* __restrict__ Q, const ushort* __restrict__ K, const ushort* __restrict__ Vt,
    const u64* __restrict__ mbits,
    ushort* __restrict__ att, float* __restrict__ marr, float* __restrict__ ilarr)
{
  __shared__ ushort lsK[2][4096];
  __shared__ ushort lsV[2][4096];
  __shared__ ushort lsP[8][1024];
  const int t = threadIdx.x;
  const int l = t & 63, w = t >> 6;
  const int g16 = l >> 4, r16 = l & 15;
  const int b = blockIdx.z, h = blockIdx.y, qt = blockIdx.x;
  const size_t ho = ((size_t)(b * HH + h)) * SB * HDD;
  const int q = qt * 128 + w * 16 + r16;   // this lane's q-row

  bf16x8 aq[2];
  #pragma unroll
  for (int ks = 0; ks < 2; ++ks)
    aq[ks] = ldb128(Q + ho + (size_t)q * HDD + ks * 32 + g16 * 8);

  f32x4 zero = {0.f, 0.f, 0.f, 0.f};
  f32x4 acc[4];
  #pragma unroll
  for (int c = 0; c < 4; c++) acc[c] = zero;
  float mrun = -3.0e38f, lrun = 0.f;

  const ushort* Kb = K + ho;
  const ushort* Vb = Vt + ho;              // same element offset for [B,H,hd,S]
  stage_kv(Kb, Vb, &lsK[0][0], &lsV[0][0], t);

  int cur = 0;
  for (int kt = 0; kt < 32; ++kt){
    __syncthreads();                       // buf[cur] staged & prev reads done
    if (kt + 1 < 32)
      stage_kv(Kb + (size_t)(kt + 1) * 4096, Vb + (size_t)(kt + 1) * 64,
               &lsK[cur ^ 1][0], &lsV[cur ^ 1][0], t);

    const char* lk = (const char*)&lsK[cur][0];
    const char* lv = (const char*)&lsV[cur][0];
    char* lp = (char*)&lsP[w][0];

    // ---- QK^T (swapped): s4[f][j] = score(k = 16f+4*g16+j, q) ----
    f32x4 s4[4];
    #pragma unroll
    for (int f = 0; f < 4; ++f){
      f32x4 z = zero;
      int row = 16 * f + r16;
      #pragma unroll
      for (int ks = 0; ks < 2; ++ks){
        bf16x8 kf = ldb128(lk + row * 128 + ((((ks << 2) + g16) ^ (row & 7)) << 4));
        z = __builtin_amdgcn_mfma_f32_16x16x32_bf16(kf, aq[ks], z, 0, 0, 0);
      }
      s4[f] = z;
    }

    // ---- mask + scale (log2 domain), lane-local online softmax ----
    u64 mw = mbits[((size_t)b * SB + q) * 32 + kt];
    float p[4][4];
    float mx = -3.0e38f;
    #pragma unroll
    for (int f = 0; f < 4; ++f)
      #pragma unroll
      for (int j = 0; j < 4; ++j){
        float v = ((mw >> (16 * f + 4 * g16 + j)) & 1ull) ? s4[f][j] * C2LOG : NEGBIG2;
        p[f][j] = v;
        mx = fmaxf(mx, v);
      }
    mx = fmaxf(mx, __shfl_xor(mx, 16));
    mx = fmaxf(mx, __shfl_xor(mx, 32));
    float mnew = fmaxf(mrun, mx);
    float alpha = exp2f(mrun - mnew);
    float rs = 0.f;
    #pragma unroll
    for (int f = 0; f < 4; ++f)
      #pragma unroll
      for (int j = 0; j < 4; ++j){
        float e = exp2f(p[f][j] - mnew);
        p[f][j] = e;
        rs += e;
      }
    rs += __shfl_xor(rs, 16);
    rs += __shfl_xor(rs, 32);
    lrun = lrun * alpha + rs;
    mrun = mnew;
    #pragma unroll
    for (int c = 0; c < 4; ++c)
      #pragma unroll
      for (int j = 0; j < 4; ++j)
        acc[c][j] *= alpha;

    // ---- P -> wave-private LDS (row q, swizzled), then read B-fragments ----
    {
      int wbase = r16 * 128 + ((g16 & 1) << 3);
      #pragma unroll
      for (int f = 0; f < 4; ++f){
        u32x2 val = { packbf(p[f][0], p[f][1]), packbf(p[f][2], p[f][3]) };
        *(u32x2*)(lp + wbase + (((2 * f + (g16 >> 1)) ^ (r16 & 7)) << 4)) = val;
      }
    }
    bf16x8 pf[2];
    #pragma unroll
    for (int ks = 0; ks < 2; ++ks)
      pf[ks] = ldb128(lp + r16 * 128 + ((((ks << 2) + g16) ^ (r16 & 7)) << 4));

    // ---- PV: acc[c] = D[d][q] += Vt-frag x P-frag ----
    #pragma unroll
    for (int c = 0; c < 4; ++c){
      int row = 16 * c + r16;
      #pragma unroll
      for (int ks = 0; ks < 2; ++ks){
        bf16x8 vf = ldb128(lv + row * 128 + ((((ks << 2) + g16) ^ (row & 7)) << 4));
        acc[c] = __builtin_amdgcn_mfma_f32_16x16x32_bf16(vf, pf[ks], acc[c], 0, 0, 0);
      }
    }
    cur ^= 1;
  }

  // ---- epilogue: O[q][d] = acc[d_local][q] / l,  d = 16c + 4*g16 + j ----
  float il = 1.0f / lrun;
  #pragma unroll
  for (int c = 0; c < 4; ++c){
    ushort4 o;
    o.x = f2bf(acc[c][0] * il); o.y = f2bf(acc[c][1] * il);
    o.z = f2bf(acc[c][2] * il); o.w = f2bf(acc[c][3] * il);
    *(ushort4*)(att + ((size_t)b * SB + q) * DD + h * HDD + c * 16 + 4 * g16) = o;
  }
  if (g16 == 0){
    marr [(size_t)(b * HH + h) * SB + q] = mrun;   // log2-domain running max
    ilarr[(size_t)(b * HH + h) * SB + q] = il;
  }
}

// ---------------- avg attention: per (b, 64-q tile, 64-k tile), loop heads ----
__global__ __launch_bounds__(256) void k_avg(
    const ushort* __restrict__ Q, const ushort* __restrict__ K,
    const u64* __restrict__ mbits, const float* __restrict__ marr,
    const float* __restrict__ ilarr, float* __restrict__ avg)
{
  __shared__ ushort lsQ[64*64];
  __shared__ ushort lsK[64*64];
  const int t = threadIdx.x;
  const int l = t & 63, w = t >> 6;
  const int g16 = l >> 4, r16 = l & 15;
  const int b = blockIdx.z, qt = blockIdx.y, kt = blockIdx.x;
  const int qbase = qt * 64, kbase = kt * 64;
  const int qr0 = qbase + w * 16 + g16 * 4;
  u64 mw[4];
  #pragma unroll
  for (int j = 0; j < 4; j++)
    mw[j] = mbits[((size_t)b * SB + qr0 + j) * 32 + kt];
  f32x4 zero = {0.f, 0.f, 0.f, 0.f};
  f32x4 acc[4];
  #pragma unroll
  for (int c = 0; c < 4; c++) acc[c] = zero;

  for (int h = 0; h < HH; ++h){
    const size_t ho = ((size_t)(b * HH + h)) * SB * HDD;
    __syncthreads();
    #pragma unroll
    for (int i = 0; i < 2; i++){
      int c = t + i * 256;
      int r = c >> 3, cg = c & 7;
      int g = cg ^ (r & 7);
      gl_lds16(Q + ho + (size_t)(qbase + r) * HDD + g * 8, (char*)lsQ + c * 16);
      gl_lds16(K + ho + (size_t)(kbase + r) * HDD + g * 8, (char*)lsK + c * 16);
    }
    __syncthreads();
    int qrow = w * 16 + r16;
    bf16x8 a0 = ldb128((char*)lsQ + qrow * 128 + (((0 + g16) ^ (qrow & 7)) << 4));
    bf16x8 a1 = ldb128((char*)lsQ + qrow * 128 + (((4 + g16) ^ (qrow & 7)) << 4));
    float mh[4], ilh[4];
    #pragma unroll
    for (int j = 0; j < 4; j++){
      mh[j]  = marr [(size_t)(b * HH + h) * SB + qr0 + j];
      ilh[j] = ilarr[(size_t)(b * HH + h) * SB + qr0 + j];
    }
    #pragma unroll
    for (int f = 0; f < 4; ++f){
      int row = 16 * f + r16;
      bf16x8 b0 = ldb128((char*)lsK + row * 128 + (((0 + g16) ^ (row & 7)) << 4));
      bf16x8 b1 = ldb128((char*)lsK + row * 128 + (((4 + g16) ^ (row & 7)) << 4));
      f32x4 z = zero;
      z = __builtin_amdgcn_mfma_f32_16x16x32_bf16(a0, b0, z, 0, 0, 0);
      z = __builtin_amdgcn_mfma_f32_16x16x32_bf16(a1, b1, z, 0, 0, 0);
      #pragma unroll
      for (int j = 0; j < 4; j++){
        int kl = 16 * f + r16;
        float s = ((mw[j] >> kl) & 1ull) ? z[j] * C2LOG : NEGBIG2;
        acc[f][j] += exp2f(s - mh[j]) * ilh[j];
      }
    }
  }
  #pragma unroll
  for (int f = 0; f < 4; f++)
    #pragma unroll
    for (int j = 0; j < 4; j++){
      int qr = qr0 + j;
      int kc = kbase + 16 * f + r16;
      avg[((size_t)b * SB + qr) * SB + kc] = acc[f][j] * 0.0625f;
    }
}

// ---------------- launch ----------------
extern "C" void kernel_launch(void* const* d_in, const int* in_sizes, int n_in,
                              void* d_out, int out_size, void* d_ws, size_t ws_size,
                              hipStream_t stream)
{
  const float* x  = (const float*)d_in[0];
  const int* mask = (const int*)d_in[1];
  const float* Wq = (const float*)d_in[2];
  const float* bq = (const float*)d_in[3];
  const float* Wk = (const float*)d_in[4];
  const float* bk = (const float*)d_in[5];
  const float* Wv = (const float*)d_in[6];
  const float* bv = (const float*)d_in[7];
  const float* Wo = (const float*)d_in[8];
  const float* bo = (const float*)d_in[9];
  float* out = (float*)d_out;
  float* avg = out + (size_t)BB * SB * DD;

  char* ws = (char*)d_ws;
  ushort* xb   = (ushort*)(ws);                 // [4096][1024] bf16, 8 MB
  ushort* wqb  = (ushort*)(ws + (8ull  << 20));
  ushort* wkb  = (ushort*)(ws + (10ull << 20));
  ushort* wvb  = (ushort*)(ws + (12ull << 20));
  ushort* wob  = (ushort*)(ws + (14ull << 20));
  ushort* Qb   = (ushort*)(ws + (16ull << 20)); // [B,H,S,hd]
  ushort* Kb   = (ushort*)(ws + (24ull << 20)); // [B,H,S,hd]
  ushort* Vtb  = (ushort*)(ws + (32ull << 20)); // [B,H,hd,S]
  ushort* att  = (ushort*)(ws + (40ull << 20)); // [B,S,D]
  float*  marr = (float*) (ws + (48ull << 20));
  float*  ilarr= (float*) (ws + (48ull << 20) + (1ull << 19));
  u64*    mbits= (u64*)   (ws + (49ull << 20));

  k_cvt<<<4096, 256, 0, stream>>>(x,  xb,  1048576);
  k_cvt<<<1024, 256, 0, stream>>>(Wq, wqb, 262144);
  k_cvt<<<1024, 256, 0, stream>>>(Wk, wkb, 262144);
  k_cvt<<<1024, 256, 0, stream>>>(Wv, wvb, 262144);
  k_cvt<<<1024, 256, 0, stream>>>(Wo, wob, 262144);
  k_pack<<<32768, 256, 0, stream>>>(mask, mbits);
  k_gemm_qk<<<dim3(8, 32, 2), 256, 0, stream>>>(xb, wqb, wkb, bq, bk, Qb, Kb);
  k_gemm_v<<<dim3(8, 32, 1), 256, 0, stream>>>(xb, wvb, bv, Vtb);
  k_flash<<<dim3(16, 16, 2), 512, 0, stream>>>(Qb, Kb, Vtb, mbits, att, marr, ilarr);
  k_avg<<<dim3(32, 32, 2), 256, 0, stream>>>(Qb, Kb, mbits, marr, ilarr, avg);
  k_gemm_out<<<dim3(8, 32, 1), 256, 0, stream>>>(att, wob, bo, out);
}

// Round 4
// 235.501 us; speedup vs baseline: 1.3055x; 1.0518x over previous
//
#include <hip/hip_runtime.h>
#include <cstdint>

typedef __bf16 bf16x8 __attribute__((ext_vector_type(8)));
typedef __bf16 bf16x4 __attribute__((ext_vector_type(4)));
typedef short  s16x8  __attribute__((ext_vector_type(8)));
typedef float  f32x4  __attribute__((ext_vector_type(4)));
typedef unsigned int uint32;
typedef uint32 u32x2 __attribute__((ext_vector_type(2)));
typedef unsigned long long u64;

#define SB 2048
#define DD 1024
#define HH 16
#define HDD 64
#define BB 2
#define C2LOG 0.2434547882f        /* (1.35/sqrt(64)) * log2(e)  — folded into Q */
#define NEGBIG2 (-1.9476383e9f)    /* -1e9 * 1.35 * log2(e) */
#define DEFER_THR 8.0f

__device__ __forceinline__ ushort f2bf(float f){
  uint32 u = __builtin_bit_cast(uint32, f);
  u += 0x7fffu + ((u >> 16) & 1u);
  return (ushort)(u >> 16);
}
__device__ __forceinline__ bf16x8 ldb128(const void* p){
  return __builtin_bit_cast(bf16x8, *(const s16x8*)p);
}
__device__ __forceinline__ void gl_lds16(const void* g, void* l){
  __builtin_amdgcn_global_load_lds((const __attribute__((address_space(1))) void*)g,
                                   (__attribute__((address_space(3))) void*)l, 16, 0, 0);
}

// ---------------- convert f32 -> bf16 ----------------
__global__ __launch_bounds__(256) void k_cvt(const float* __restrict__ in,
                                             ushort* __restrict__ out, int n4){
  int i = blockIdx.x * 256 + threadIdx.x;
  if (i < n4){
    float4 v = ((const float4*)in)[i];
    ushort4 o;
    o.x = f2bf(v.x); o.y = f2bf(v.y); o.z = f2bf(v.z); o.w = f2bf(v.w);
    ((ushort4*)out)[i] = o;
  }
}

// ---------------- pack mask ints into 64-bit words ----------------
__global__ __launch_bounds__(256) void k_pack(const int* __restrict__ mask,
                                              u64* __restrict__ bits){
  int i = blockIdx.x * 256 + threadIdx.x;
  u64 b = __ballot(mask[i] != 0);
  if ((threadIdx.x & 63) == 0) bits[i >> 6] = b;
}

// ---------------- generic GEMM: C[r][n] = (sum_k A[r][k]*W[n][k] + bias[n])*scl
// MODE 0: bf16 [B,H,S,hd]; MODE 1: f32 [B*S,D]; MODE 2: bf16 transposed [B,H,hd,S]
template<int MODE>
__device__ __forceinline__ void gemm_body(
    const ushort* __restrict__ A, const ushort* __restrict__ W,
    const float* __restrict__ bias, float scl,
    ushort* __restrict__ outp, float* __restrict__ outf)
{
  __shared__ ushort lsA[128*32];
  __shared__ ushort lsB[128*32];
  const int t = threadIdx.x;
  const int l = t & 63, w = t >> 6;
  const int g16 = l >> 4, r16 = l & 15;
  const int wr = w >> 1, wc = w & 1;
  const int rowBase = blockIdx.y * 128;
  const int colBase = blockIdx.x * 128;
  f32x4 zero = {0.f, 0.f, 0.f, 0.f};
  f32x4 acc[4][4];
  #pragma unroll
  for (int m = 0; m < 4; m++)
    #pragma unroll
    for (int n = 0; n < 4; n++) acc[m][n] = zero;

  for (int kt = 0; kt < 32; ++kt){
    __syncthreads();
    #pragma unroll
    for (int i = 0; i < 2; i++){
      int c = t + i * 256;
      int row = c >> 2, cin = c & 3;
      int g = cin ^ ((row >> 1) & 3);
      gl_lds16(A + (size_t)(rowBase + row) * DD + kt * 32 + g * 8, (char*)lsA + c * 16);
      gl_lds16(W + (size_t)(colBase + row) * DD + kt * 32 + g * 8, (char*)lsB + c * 16);
    }
    __syncthreads();
    bf16x8 af[4], bfr[4];
    #pragma unroll
    for (int m = 0; m < 4; m++){
      int row = wr * 64 + m * 16 + r16;
      af[m] = ldb128((char*)lsA + row * 64 + ((g16 ^ ((row >> 1) & 3)) << 4));
    }
    #pragma unroll
    for (int n = 0; n < 4; n++){
      int row = wc * 64 + n * 16 + r16;
      bfr[n] = ldb128((char*)lsB + row * 64 + ((g16 ^ ((row >> 1) & 3)) << 4));
    }
    #pragma unroll
    for (int m = 0; m < 4; m++)
      #pragma unroll
      for (int n = 0; n < 4; n++)
        acc[m][n] = __builtin_amdgcn_mfma_f32_16x16x32_bf16(af[m], bfr[n], acc[m][n], 0, 0, 0);
  }
  #pragma unroll
  for (int m = 0; m < 4; m++){
    #pragma unroll
    for (int n = 0; n < 4; n++){
      int ng = colBase + wc * 64 + n * 16 + r16;
      float bval = bias[ng];
      if (MODE == 2){
        int h = ng >> 6, d = ng & 63;
        int s0 = rowBase + wr * 64 + m * 16 + g16 * 4;
        int b = s0 >> 11, s = s0 & 2047;
        ushort4 o;
        o.x = f2bf((acc[m][n][0] + bval) * scl);
        o.y = f2bf((acc[m][n][1] + bval) * scl);
        o.z = f2bf((acc[m][n][2] + bval) * scl);
        o.w = f2bf((acc[m][n][3] + bval) * scl);
        *(ushort4*)(outp + ((size_t)(b * HH + h) * HDD + d) * SB + s) = o;
      } else {
        #pragma unroll
        for (int j = 0; j < 4; j++){
          int r = rowBase + wr * 64 + m * 16 + g16 * 4 + j;
          float v = (acc[m][n][j] + bval) * scl;
          if (MODE == 0){
            int h = ng >> 6, d = ng & 63;
            int b = r >> 11, s = r & 2047;
            outp[(((size_t)(b * HH + h) * SB + s) << 6) + d] = f2bf(v);
          } else {
            outf[(size_t)r * DD + ng] = v;
          }
        }
      }
    }
  }
}

__global__ __launch_bounds__(256) void k_gemm_qk(
    const ushort* __restrict__ A,
    const ushort* __restrict__ Wq, const ushort* __restrict__ Wk,
    const float* __restrict__ bq, const float* __restrict__ bk,
    ushort* __restrict__ Q, ushort* __restrict__ K)
{
  int z = blockIdx.z;
  gemm_body<0>(A, z ? Wk : Wq, z ? bk : bq, z ? 1.0f : C2LOG, z ? K : Q, nullptr);
}

__global__ __launch_bounds__(256) void k_gemm_v(
    const ushort* __restrict__ A, const ushort* __restrict__ Wv,
    const float* __restrict__ bv, ushort* __restrict__ Vt)
{
  gemm_body<2>(A, Wv, bv, 1.0f, Vt, nullptr);
}

__global__ __launch_bounds__(256) void k_gemm_out(
    const ushort* __restrict__ A, const ushort* __restrict__ Wo,
    const float* __restrict__ bo, float* __restrict__ out)
{
  gemm_body<1>(A, Wo, bo, 1.0f, nullptr, out);
}

// ---------------- flash attention (swapped QK^T, P via wave-private LDS) -----
// 8 waves x 16 q-rows = 128 q-rows/block; KVBLK=64, double-buffered K/Vt LDS.
__device__ __forceinline__ void stage_kv(const ushort* __restrict__ Kp,
                                         const ushort* __restrict__ Vtp,
                                         ushort* dK, ushort* dV, int t){
  int r = t >> 3, g = (t & 7) ^ (r & 7);
  gl_lds16(Kp + (size_t)r * HDD + g * 8, (char*)dK + t * 16);
  gl_lds16(Vtp + (size_t)r * SB + g * 8, (char*)dV + t * 16);
}

__global__ __launch_bounds__(512) void k_flash(
    const ushort* __restrict__ Q, const ushort* __restrict__ K, const ushort* __restrict__ Vt,
    const u64* __restrict__ mbits,
    ushort* __restrict__ att, float* __restrict__ marr, float* __restrict__ ilarr)
{
  __shared__ ushort lsK[2][4096];
  __shared__ ushort lsV[2][4096];
  __shared__ ushort lsP[8][1024];
  const int t = threadIdx.x;
  const int l = t & 63, w = t >> 6;
  const int g16 = l >> 4, r16 = l & 15;
  const int b = blockIdx.z, h = blockIdx.y, qt = blockIdx.x;
  const size_t ho = ((size_t)(b * HH + h)) * SB * HDD;
  const int q = qt * 128 + w * 16 + r16;   // this lane's q-row

  bf16x8 aq[2];
  #pragma unroll
  for (int ks = 0; ks < 2; ++ks)
    aq[ks] = ldb128(Q + ho + (size_t)q * HDD + ks * 32 + g16 * 8);

  const u64* mp = mbits + ((size_t)b * SB + q) * 32;

  f32x4 zero = {0.f, 0.f, 0.f, 0.f};
  f32x4 acc[4];
  #pragma unroll
  for (int c = 0; c < 4; c++) acc[c] = zero;
  float mrun = -3.0e38f, lrun = 0.f;

  const ushort* Kb = K + ho;
  const ushort* Vb = Vt + ho;
  stage_kv(Kb, Vb, &lsK[0][0], &lsV[0][0], t);

  int cur = 0;
  for (int kt = 0; kt < 32; ++kt){
    __syncthreads();                       // buf[cur] staged & prev reads done
    if (kt + 1 < 32)
      stage_kv(Kb + (size_t)(kt + 1) * 4096, Vb + (size_t)(kt + 1) * 64,
               &lsK[cur ^ 1][0], &lsV[cur ^ 1][0], t);

    const char* lk = (const char*)&lsK[cur][0];
    const char* lv = (const char*)&lsV[cur][0];
    char* lp = (char*)&lsP[w][0];

    // ---- QK^T (swapped): s4[f][j] = score(k = 16f+4*g16+j, q), pre-scaled ----
    f32x4 s4[4];
    __builtin_amdgcn_s_setprio(1);
    #pragma unroll
    for (int f = 0; f < 4; ++f){
      f32x4 z = zero;
      int row = 16 * f + r16;
      #pragma unroll
      for (int ks = 0; ks < 2; ++ks){
        bf16x8 kf = ldb128(lk + row * 128 + ((((ks << 2) + g16) ^ (row & 7)) << 4));
        z = __builtin_amdgcn_mfma_f32_16x16x32_bf16(kf, aq[ks], z, 0, 0, 0);
      }
      s4[f] = z;
    }
    __builtin_amdgcn_s_setprio(0);

    // ---- mask (wave fast path), lane-local online softmax (log2 domain) ----
    u64 mw = mp[kt];
    float p[4][4];
    float mx = -3.0e38f;
    if (__all(mw == ~0ull)){
      #pragma unroll
      for (int f = 0; f < 4; ++f)
        #pragma unroll
        for (int j = 0; j < 4; ++j){
          p[f][j] = s4[f][j];
          mx = fmaxf(mx, s4[f][j]);
        }
    } else {
      #pragma unroll
      for (int f = 0; f < 4; ++f)
        #pragma unroll
        for (int j = 0; j < 4; ++j){
          float v = ((mw >> (16 * f + 4 * g16 + j)) & 1ull) ? s4[f][j] : NEGBIG2;
          p[f][j] = v;
          mx = fmaxf(mx, v);
        }
    }
    mx = fmaxf(mx, __shfl_xor(mx, 16));
    mx = fmaxf(mx, __shfl_xor(mx, 32));
    // defer-max: only rescale when tile max grew past threshold
    if (__any(mx > mrun + DEFER_THR)){
      float mnew = fmaxf(mrun, mx);
      float alpha = exp2f(mrun - mnew);
      lrun *= alpha;
      #pragma unroll
      for (int c = 0; c < 4; ++c)
        #pragma unroll
        for (int j = 0; j < 4; ++j)
          acc[c][j] *= alpha;
      mrun = mnew;
    }
    float rs = 0.f;
    #pragma unroll
    for (int f = 0; f < 4; ++f)
      #pragma unroll
      for (int j = 0; j < 4; ++j){
        float e = exp2f(p[f][j] - mrun);
        p[f][j] = e;
        rs += e;
      }
    rs += __shfl_xor(rs, 16);
    rs += __shfl_xor(rs, 32);
    lrun += rs;

    // ---- P -> wave-private LDS (native bf16 casts -> v_cvt_pk), read back ----
    {
      int wbase = r16 * 128 + ((g16 & 1) << 3);
      #pragma unroll
      for (int f = 0; f < 4; ++f){
        bf16x4 pv = { (__bf16)p[f][0], (__bf16)p[f][1], (__bf16)p[f][2], (__bf16)p[f][3] };
        *(u32x2*)(lp + wbase + (((2 * f + (g16 >> 1)) ^ (r16 & 7)) << 4)) =
            __builtin_bit_cast(u32x2, pv);
      }
    }
    bf16x8 pf[2];
    #pragma unroll
    for (int ks = 0; ks < 2; ++ks)
      pf[ks] = ldb128(lp + r16 * 128 + ((((ks << 2) + g16) ^ (r16 & 7)) << 4));

    // ---- PV: acc[c] = D[d][q] += Vt-frag x P-frag ----
    __builtin_amdgcn_s_setprio(1);
    #pragma unroll
    for (int c = 0; c < 4; ++c){
      int row = 16 * c + r16;
      #pragma unroll
      for (int ks = 0; ks < 2; ++ks){
        bf16x8 vf = ldb128(lv + row * 128 + ((((ks << 2) + g16) ^ (row & 7)) << 4));
        acc[c] = __builtin_amdgcn_mfma_f32_16x16x32_bf16(vf, pf[ks], acc[c], 0, 0, 0);
      }
    }
    __builtin_amdgcn_s_setprio(0);
    cur ^= 1;
  }

  // ---- epilogue ----
  float il = 1.0f / lrun;
  #pragma unroll
  for (int c = 0; c < 4; ++c){
    ushort4 o;
    o.x = f2bf(acc[c][0] * il); o.y = f2bf(acc[c][1] * il);
    o.z = f2bf(acc[c][2] * il); o.w = f2bf(acc[c][3] * il);
    *(ushort4*)(att + ((size_t)b * SB + q) * DD + h * HDD + c * 16 + 4 * g16) = o;
  }
  if (g16 == 0){
    marr [(size_t)(b * HH + h) * SB + q] = mrun;   // log2-domain (deferred) max
    ilarr[(size_t)(b * HH + h) * SB + q] = il;
  }
}

// ---------------- avg attention: (b, 64-q, 64-k) block, dbuf over heads ------
__device__ __forceinline__ void stage_qk(const ushort* __restrict__ Qp,
                                         const ushort* __restrict__ Kp,
                                         ushort* dQ, ushort* dK, int t){
  #pragma unroll
  for (int i = 0; i < 2; i++){
    int c = t + i * 256;
    int r = c >> 3, g = (c & 7) ^ (r & 7);
    gl_lds16(Qp + (size_t)r * HDD + g * 8, (char*)dQ + c * 16);
    gl_lds16(Kp + (size_t)r * HDD + g * 8, (char*)dK + c * 16);
  }
}

__global__ __launch_bounds__(256) void k_avg(
    const ushort* __restrict__ Q, const ushort* __restrict__ K,
    const u64* __restrict__ mbits, const float* __restrict__ marr,
    const float* __restrict__ ilarr, float* __restrict__ avg)
{
  __shared__ ushort lsQ[2][4096];
  __shared__ ushort lsK[2][4096];
  const int t = threadIdx.x;
  const int l = t & 63, w = t >> 6;
  const int g16 = l >> 4, r16 = l & 15;
  const int b = blockIdx.z, qt = blockIdx.y, kt = blockIdx.x;
  const int qbase = qt * 64, kbase = kt * 64;
  const int qr0 = qbase + w * 16 + g16 * 4;
  u64 mw[4];
  #pragma unroll
  for (int j = 0; j < 4; j++)
    mw[j] = mbits[((size_t)b * SB + qr0 + j) * 32 + kt];
  bool allv = (mw[0] & mw[1] & mw[2] & mw[3]) == ~0ull;
  bool wave_allv = __all(allv);
  f32x4 zero = {0.f, 0.f, 0.f, 0.f};
  f32x4 acc[4];
  #pragma unroll
  for (int c = 0; c < 4; c++) acc[c] = zero;

  const size_t hstep = (size_t)SB * HDD;
  const ushort* Qp = Q + (size_t)b * HH * hstep + (size_t)qbase * HDD;
  const ushort* Kp = K + (size_t)b * HH * hstep + (size_t)kbase * HDD;
  stage_qk(Qp, Kp, &lsQ[0][0], &lsK[0][0], t);

  int cur = 0;
  for (int h = 0; h < HH; ++h){
    __syncthreads();
    if (h + 1 < HH)
      stage_qk(Qp + (size_t)(h + 1) * hstep, Kp + (size_t)(h + 1) * hstep,
               &lsQ[cur ^ 1][0], &lsK[cur ^ 1][0], t);
    const char* lq = (const char*)&lsQ[cur][0];
    const char* lk = (const char*)&lsK[cur][0];

    int qrow = w * 16 + r16;
    bf16x8 a0 = ldb128(lq + qrow * 128 + (((0 + g16) ^ (qrow & 7)) << 4));
    bf16x8 a1 = ldb128(lq + qrow * 128 + (((4 + g16) ^ (qrow & 7)) << 4));
    float mh[4], ilh[4];
    #pragma unroll
    for (int j = 0; j < 4; j++){
      mh[j]  = marr [(size_t)(b * HH + h) * SB + qr0 + j];
      ilh[j] = ilarr[(size_t)(b * HH + h) * SB + qr0 + j];
    }
    #pragma unroll
    for (int f = 0; f < 4; ++f){
      int row = 16 * f + r16;
      bf16x8 b0 = ldb128(lk + row * 128 + (((0 + g16) ^ (row & 7)) << 4));
      bf16x8 b1 = ldb128(lk + row * 128 + (((4 + g16) ^ (row & 7)) << 4));
      f32x4 z = zero;
      z = __builtin_amdgcn_mfma_f32_16x16x32_bf16(a0, b0, z, 0, 0, 0);
      z = __builtin_amdgcn_mfma_f32_16x16x32_bf16(a1, b1, z, 0, 0, 0);
      if (wave_allv){
        #pragma unroll
        for (int j = 0; j < 4; j++)
          acc[f][j] += exp2f(z[j] - mh[j]) * ilh[j];
      } else {
        #pragma unroll
        for (int j = 0; j < 4; j++){
          int kl = 16 * f + r16;
          float s = ((mw[j] >> kl) & 1ull) ? z[j] : NEGBIG2;
          acc[f][j] += exp2f(s - mh[j]) * ilh[j];
        }
      }
    }
    cur ^= 1;
  }
  #pragma unroll
  for (int f = 0; f < 4; f++)
    #pragma unroll
    for (int j = 0; j < 4; j++){
      int qr = qr0 + j;
      int kc = kbase + 16 * f + r16;
      avg[((size_t)b * SB + qr) * SB + kc] = acc[f][j] * 0.0625f;
    }
}

// ---------------- launch ----------------
extern "C" void kernel_launch(void* const* d_in, const int* in_sizes, int n_in,
                              void* d_out, int out_size, void* d_ws, size_t ws_size,
                              hipStream_t stream)
{
  const float* x  = (const float*)d_in[0];
  const int* mask = (const int*)d_in[1];
  const float* Wq = (const float*)d_in[2];
  const float* bq = (const float*)d_in[3];
  const float* Wk = (const float*)d_in[4];
  const float* bk = (const float*)d_in[5];
  const float* Wv = (const float*)d_in[6];
  const float* bv = (const float*)d_in[7];
  const float* Wo = (const float*)d_in[8];
  const float* bo = (const float*)d_in[9];
  float* out = (float*)d_out;
  float* avg = out + (size_t)BB * SB * DD;

  char* ws = (char*)d_ws;
  ushort* xb   = (ushort*)(ws);                 // [4096][1024] bf16, 8 MB
  ushort* wqb  = (ushort*)(ws + (8ull  << 20));
  ushort* wkb  = (ushort*)(ws + (10ull << 20));
  ushort* wvb  = (ushort*)(ws + (12ull << 20));
  ushort* wob  = (ushort*)(ws + (14ull << 20));
  ushort* Qb   = (ushort*)(ws + (16ull << 20)); // [B,H,S,hd] (pre-scaled by C2LOG)
  ushort* Kb   = (ushort*)(ws + (24ull << 20)); // [B,H,S,hd]
  ushort* Vtb  = (ushort*)(ws + (32ull << 20)); // [B,H,hd,S]
  ushort* att  = (ushort*)(ws + (40ull << 20)); // [B,S,D]
  float*  marr = (float*) (ws + (48ull << 20));
  float*  ilarr= (float*) (ws + (48ull << 20) + (1ull << 19));
  u64*    mbits= (u64*)   (ws + (49ull << 20));

  k_cvt<<<4096, 256, 0, stream>>>(x,  xb,  1048576);
  k_cvt<<<1024, 256, 0, stream>>>(Wq, wqb, 262144);
  k_cvt<<<1024, 256, 0, stream>>>(Wk, wkb, 262144);
  k_cvt<<<1024, 256, 0, stream>>>(Wv, wvb, 262144);
  k_cvt<<<1024, 256, 0, stream>>>(Wo, wob, 262144);
  k_pack<<<32768, 256, 0, stream>>>(mask, mbits);
  k_gemm_qk<<<dim3(8, 32, 2), 256, 0, stream>>>(xb, wqb, wkb, bq, bk, Qb, Kb);
  k_gemm_v<<<dim3(8, 32, 1), 256, 0, stream>>>(xb, wvb, bv, Vtb);
  k_flash<<<dim3(16, 16, 2), 512, 0, stream>>>(Qb, Kb, Vtb, mbits, att, marr, ilarr);
  k_avg<<<dim3(32, 32, 2), 256, 0, stream>>>(Qb, Kb, mbits, marr, ilarr, avg);
  k_gemm_out<<<dim3(8, 32, 1), 256, 0, stream>>>(att, wob, bo, out);
}